// Round 1
// baseline (295.062 us; speedup 1.0000x reference)
//
#include <hip/hip_runtime.h>
#include <hip/hip_bf16.h>

// GraphSAGE 2-layer, mean agg, D=64, fp32 in/out.
// R9: all intermediate node features stored as bf16 (x_bf16, agg, h1) —
//     halves the random-gather traffic (128 B rows) and feeds MFMA directly.
// R10: gather restructured for memory-level parallelism.
//     - ELL rows sentinel-padded to a multiple of 8 (sentinel = node N, an
//       all-zero feature row) so the inner loop has NO divergent per-load
//       guards: 8 row loads issue back-to-back per burst.
//     - uint4 loads, 8 lanes per 128 B row, 8 nodes per wave (was uint2/16).
//       Each load instruction now covers 8 cachelines -> ~64 lines in
//       flight per wave vs ~4 before (gather was latency-bound, 23% VALU,
//       28% HBM).

#define D 64
#define CAP 64          // ELL row capacity
#define BNODES 256      // nodes per bucket (bucket = dst >> 8)
#define BCAP 4736       // bucket edge capacity: Poisson(4096), +10 sigma
#define MAXNB 512

typedef __bf16 bf16x8 __attribute__((ext_vector_type(8)));
typedef float  f32x4  __attribute__((ext_vector_type(4)));

__device__ __forceinline__ unsigned pack2(float a, float b) {
    __hip_bfloat162 t = __float22bfloat162_rn(make_float2(a, b));
    return *(unsigned*)&t;
}
__device__ __forceinline__ unsigned short f2b(float f) {
    __hip_bfloat16 b = __float2bfloat16(f);
    return *(unsigned short*)&b;
}

// ---- x -> bf16 ----------------------------------------------------------

__global__ void __launch_bounds__(256)
cvt_kernel(const float4* __restrict__ x, uint4* __restrict__ y, int n8) {
    int i = blockIdx.x * blockDim.x + threadIdx.x;
    if (i < n8) {
        float4 a = x[2 * i], b = x[2 * i + 1];
        uint4 o;
        o.x = pack2(a.x, a.y);
        o.y = pack2(a.z, a.w);
        o.z = pack2(b.x, b.y);
        o.w = pack2(b.z, b.w);
        y[i] = o;
    }
}

// ---- zero the sentinel row (index N) of xb and h1b ----------------------

__global__ void __launch_bounds__(64)
zrow_kernel(unsigned* __restrict__ a, unsigned* __restrict__ b) {
    int t = threadIdx.x;
    if (t < 32) a[t] = 0u;
    else        b[t - 32] = 0u;
}

// ---- Phase 1: bin edges by dst range ------------------------------------

__global__ void __launch_bounds__(256)
bin_kernel(const int* __restrict__ src, const int* __restrict__ dst,
           int* __restrict__ gcur, int* __restrict__ gbucket, int E, int NB) {
    __shared__ int hist[MAXNB];
    for (int i = threadIdx.x; i < NB; i += 256) hist[i] = 0;
    __syncthreads();

    const int t        = threadIdx.x;
    const int e4_total = E >> 2;
    const int base4    = blockIdx.x * 1024;

    int4 sv[4], dv[4];
    bool have[4];
    #pragma unroll
    for (int k = 0; k < 4; ++k) {
        int i4 = base4 + t + k * 256;
        have[k] = i4 < e4_total;
        if (have[k]) {
            sv[k] = ((const int4*)src)[i4];
            dv[k] = ((const int4*)dst)[i4];
        }
    }

    #pragma unroll
    for (int k = 0; k < 4; ++k) if (have[k]) {
        atomicAdd(&hist[dv[k].x >> 8], 1);
        atomicAdd(&hist[dv[k].y >> 8], 1);
        atomicAdd(&hist[dv[k].z >> 8], 1);
        atomicAdd(&hist[dv[k].w >> 8], 1);
    }

    int  tail_s = 0, tail_d = 0;
    bool have_tail = false;
    if (blockIdx.x == 0) {
        int e = (e4_total << 2) + t;
        if (e < E) {
            tail_s = src[e]; tail_d = dst[e]; have_tail = true;
            atomicAdd(&hist[tail_d >> 8], 1);
        }
    }
    __syncthreads();

    for (int i = threadIdx.x; i < NB; i += 256) {
        int c = hist[i];
        hist[i] = (c > 0) ? atomicAdd(&gcur[i], c) : 0;
    }
    __syncthreads();

    #pragma unroll
    for (int k = 0; k < 4; ++k) if (have[k]) {
        int4 s = sv[k], d = dv[k];
        int b, p;
        b = d.x >> 8; p = atomicAdd(&hist[b], 1); if (p < BCAP) gbucket[b * BCAP + p] = ((d.x & 255) << 17) | s.x;
        b = d.y >> 8; p = atomicAdd(&hist[b], 1); if (p < BCAP) gbucket[b * BCAP + p] = ((d.y & 255) << 17) | s.y;
        b = d.z >> 8; p = atomicAdd(&hist[b], 1); if (p < BCAP) gbucket[b * BCAP + p] = ((d.z & 255) << 17) | s.z;
        b = d.w >> 8; p = atomicAdd(&hist[b], 1); if (p < BCAP) gbucket[b * BCAP + p] = ((d.w & 255) << 17) | s.w;
    }
    if (have_tail) {
        int b = tail_d >> 8, p = atomicAdd(&hist[b], 1);
        if (p < BCAP) gbucket[b * BCAP + p] = ((tail_d & 255) << 17) | tail_s;
    }
}

// ---- Phase 2: per-bucket ELL build (64 KB L2-resident window) -----------
// Pads each node's edge list up to a multiple of 8 with sentinel index N
// (an all-zero feature row) so the gather inner loop is branchless.

__global__ void __launch_bounds__(256)
ellify_kernel(const int* __restrict__ gcur, const int* __restrict__ gbucket,
              int* __restrict__ cnt, int* __restrict__ edge_idx, int N) {
    __shared__ int scnt[BNODES];
    scnt[threadIdx.x] = 0;
    __syncthreads();

    const int b     = blockIdx.x;
    const int ne    = min(gcur[b], BCAP);
    const int node0 = b << 8;

    for (int e = threadIdx.x; e < ne; e += 256) {
        int p   = gbucket[b * BCAP + e];
        int s   = p & 0x1FFFF;
        int ld  = p >> 17;
        int pos = atomicAdd(&scnt[ld], 1);
        if (pos < CAP) edge_idx[(size_t)(node0 + ld) * CAP + pos] = s;
    }
    __syncthreads();

    int node = node0 + threadIdx.x;
    if (node < N) {
        int raw = scnt[threadIdx.x];
        cnt[node] = raw;
        int c  = min(raw, CAP);
        int c8 = (c + 7) & ~7;            // <= CAP since CAP % 8 == 0
        for (int p = c; p < c8; ++p)
            edge_idx[(size_t)node * CAP + p] = N;   // sentinel: zero row
    }
}

// ---- Gather (bf16 rows): agg[n] = mean of neighbor rows -----------------
// 8 lanes per node; lane q covers bytes [16q, 16q+16) of the 128 B row.
// Bursts of 8 edges, all loads unconditional (sentinel-padded lists).

__device__ __forceinline__ void acc8(float* a, uint4 u) {
    a[0] += __uint_as_float(u.x << 16);
    a[1] += __uint_as_float(u.x & 0xffff0000u);
    a[2] += __uint_as_float(u.y << 16);
    a[3] += __uint_as_float(u.y & 0xffff0000u);
    a[4] += __uint_as_float(u.z << 16);
    a[5] += __uint_as_float(u.z & 0xffff0000u);
    a[6] += __uint_as_float(u.w << 16);
    a[7] += __uint_as_float(u.w & 0xffff0000u);
}

__global__ void __launch_bounds__(256, 8)
gather_kernel(const unsigned short* __restrict__ h,
              const int* __restrict__ cnt,
              const int* __restrict__ edge_idx,
              unsigned short* __restrict__ agg, int N) {
    const int lane = threadIdx.x & 63;
    const int q    = lane & 7;                  // 8 lanes x 16 B = 128 B row
    const int g    = lane >> 3;                 // 8 nodes per wave
    const int wave = blockIdx.x * (blockDim.x >> 6) + (threadIdx.x >> 6);
    const int node = wave * 8 + g;
    if (node >= N) return;

    const uint4* __restrict__ h4 = (const uint4*)h;   // row = 8 uint4

    const int count = min(cnt[node], CAP);
    const int c8    = (count + 7) & ~7;
    const int start = node * CAP;

    float acc[8] = {0.f, 0.f, 0.f, 0.f, 0.f, 0.f, 0.f, 0.f};

    for (int j = 0; j < c8; j += 8) {
        const int sreg = edge_idx[start + j + q];
        const int b0 = g << 3;
        const int s0 = __shfl(sreg, b0 + 0, 64);
        const int s1 = __shfl(sreg, b0 + 1, 64);
        const int s2 = __shfl(sreg, b0 + 2, 64);
        const int s3 = __shfl(sreg, b0 + 3, 64);
        const int s4 = __shfl(sreg, b0 + 4, 64);
        const int s5 = __shfl(sreg, b0 + 5, 64);
        const int s6 = __shfl(sreg, b0 + 6, 64);
        const int s7 = __shfl(sreg, b0 + 7, 64);
        // 8 unconditional loads -> 8 vmem instrs in flight, 8 cachelines each
        uint4 u0 = h4[(size_t)s0 * 8 + q];
        uint4 u1 = h4[(size_t)s1 * 8 + q];
        uint4 u2 = h4[(size_t)s2 * 8 + q];
        uint4 u3 = h4[(size_t)s3 * 8 + q];
        uint4 u4 = h4[(size_t)s4 * 8 + q];
        uint4 u5 = h4[(size_t)s5 * 8 + q];
        uint4 u6 = h4[(size_t)s6 * 8 + q];
        uint4 u7 = h4[(size_t)s7 * 8 + q];
        acc8(acc, u0);
        acc8(acc, u1);
        acc8(acc, u2);
        acc8(acc, u3);
        acc8(acc, u4);
        acc8(acc, u5);
        acc8(acc, u6);
        acc8(acc, u7);
    }

    const float inv = 1.0f / fmaxf((float)count, 1.0f);
    uint4 o;
    o.x = pack2(acc[0] * inv, acc[1] * inv);
    o.y = pack2(acc[2] * inv, acc[3] * inv);
    o.z = pack2(acc[4] * inv, acc[5] * inv);
    o.w = pack2(acc[6] * inv, acc[7] * inv);
    ((uint4*)agg)[node * 8 + q] = o;
}

// ---- Combine (MFMA): out = [h|agg] @ [Wself;Wneigh] + b -----------------
// A-frag (16x16x32 bf16): row m = lane&15,  k = quad*8 + j
// C/D:                    col  = lane&15,  row = quad*4 + reg

__device__ __forceinline__ bf16x8 cvt8(float4 a, float4 b) {
    union { bf16x8 v; __hip_bfloat162 p[4]; } u;
    u.p[0] = __float22bfloat162_rn(make_float2(a.x, a.y));
    u.p[1] = __float22bfloat162_rn(make_float2(a.z, a.w));
    u.p[2] = __float22bfloat162_rn(make_float2(b.x, b.y));
    u.p[3] = __float22bfloat162_rn(make_float2(b.z, b.w));
    return u.v;
}
__device__ __forceinline__ bf16x8 asbf(uint4 u) {
    union { uint4 a; bf16x8 v; } c; c.a = u; return c.v;
}

__global__ void __launch_bounds__(256)
combine_kernel(const unsigned short* __restrict__ h,
               const unsigned short* __restrict__ agg,
               const float* __restrict__ Wself,
               const float* __restrict__ Wneigh,
               const float* __restrict__ bias,
               float* __restrict__ out_f32,
               unsigned short* __restrict__ out_bf16, int N) {
    const int lane = threadIdx.x & 63;
    const int col  = lane & 15;
    const int quad = lane >> 4;
    const int wave = blockIdx.x * (blockDim.x >> 6) + (threadIdx.x >> 6);
    const int n_waves = gridDim.x * (blockDim.x >> 6);

    // B fragments: Bf[nt][kk], n = nt*16+col, k = kk*32 + quad*8 + j.
    bf16x8 Bf[4][4];
    #pragma unroll
    for (int nt = 0; nt < 4; ++nt) {
        const int n = nt * 16 + col;
        #pragma unroll
        for (int kk = 0; kk < 4; ++kk) {
            const float* W = (kk < 2) ? Wself : Wneigh;
            const int kbase = (kk & 1) * 32 + quad * 8;
            float w0 = W[(kbase + 0) * D + n];
            float w1 = W[(kbase + 1) * D + n];
            float w2 = W[(kbase + 2) * D + n];
            float w3 = W[(kbase + 3) * D + n];
            float w4 = W[(kbase + 4) * D + n];
            float w5 = W[(kbase + 5) * D + n];
            float w6 = W[(kbase + 6) * D + n];
            float w7 = W[(kbase + 7) * D + n];
            Bf[nt][kk] = cvt8(make_float4(w0, w1, w2, w3), make_float4(w4, w5, w6, w7));
        }
    }

    float bv[4];
    #pragma unroll
    for (int nt = 0; nt < 4; ++nt) bv[nt] = bias[nt * 16 + col];

    const uint4* __restrict__ h4 = (const uint4*)h;     // row = 8 uint4
    const uint4* __restrict__ a4 = (const uint4*)agg;

    const int tiles = (N + 15) >> 4;
    for (int t = wave; t < tiles; t += n_waves) {
        int row = t * 16 + col;
        if (row >= N) row = N - 1;   // clamp; stores are guarded

        // A-frags load directly as bf16x8 (one uint4 each)
        bf16x8 A0 = asbf(h4[(size_t)row * 8 + quad]);
        bf16x8 A1 = asbf(h4[(size_t)row * 8 + 4 + quad]);
        bf16x8 A2 = asbf(a4[(size_t)row * 8 + quad]);
        bf16x8 A3 = asbf(a4[(size_t)row * 8 + 4 + quad]);

        #pragma unroll
        for (int nt = 0; nt < 4; ++nt) {
            f32x4 acc = {bv[nt], bv[nt], bv[nt], bv[nt]};
            acc = __builtin_amdgcn_mfma_f32_16x16x32_bf16(A0, Bf[nt][0], acc, 0, 0, 0);
            acc = __builtin_amdgcn_mfma_f32_16x16x32_bf16(A1, Bf[nt][1], acc, 0, 0, 0);
            acc = __builtin_amdgcn_mfma_f32_16x16x32_bf16(A2, Bf[nt][2], acc, 0, 0, 0);
            acc = __builtin_amdgcn_mfma_f32_16x16x32_bf16(A3, Bf[nt][3], acc, 0, 0, 0);
            if (out_f32) {
                #pragma unroll
                for (int r = 0; r < 4; ++r) {
                    const int orow = t * 16 + quad * 4 + r;
                    if (orow < N) out_f32[(size_t)orow * D + nt * 16 + col] = acc[r];
                }
            } else {
                #pragma unroll
                for (int r = 0; r < 4; ++r) {
                    const int orow = t * 16 + quad * 4 + r;
                    if (orow < N) out_bf16[(size_t)orow * D + nt * 16 + col] = f2b(acc[r]);
                }
            }
        }
    }
}

// -------------------------------------------------------------------------

extern "C" void kernel_launch(void* const* d_in, const int* in_sizes, int n_in,
                              void* d_out, int out_size, void* d_ws, size_t ws_size,
                              hipStream_t stream) {
    const float* x   = (const float*)d_in[0];
    const int*   src = (const int*)d_in[1];
    const int*   dst = (const int*)d_in[2];
    const float* Ws1 = (const float*)d_in[3];
    const float* Wn1 = (const float*)d_in[4];
    const float* b1  = (const float*)d_in[5];
    const float* Ws2 = (const float*)d_in[6];
    const float* Wn2 = (const float*)d_in[7];
    const float* b2  = (const float*)d_in[8];

    const int N = in_sizes[0] / D;   // 100000
    const int E = in_sizes[1];       // 1600000

    float* out = (float*)d_out;

    const int NB = (N + BNODES - 1) / BNODES;   // 391 buckets

    // Workspace: gcur[512] | cnt[N] | edge_idx[N*CAP] (25.6 MB) |
    //            xb[(N+1)*D] bf16 | h1b[(N+1)*D] bf16 | aggb[N*D] bf16
    // (xb/h1b carry one extra all-zero sentinel row at index N)
    // gbucket (7.4 MB) aliases aggb — dead before gather writes agg.
    int* gcur      = (int*)d_ws;
    int* cnt       = gcur + 512;
    int* edge_idx  = cnt + N;
    unsigned short* xb   = (unsigned short*)(edge_idx + (size_t)N * CAP);
    unsigned short* h1b  = xb + (size_t)(N + 1) * D;
    unsigned short* aggb = h1b + (size_t)(N + 1) * D;
    int* gbucket   = (int*)aggb;

    // ---- x -> bf16 (independent of build) + sentinel rows ----
    const int n8 = N * D / 8;
    cvt_kernel<<<(n8 + 255) / 256, 256, 0, stream>>>((const float4*)x, (uint4*)xb, n8);
    zrow_kernel<<<1, 64, 0, stream>>>((unsigned*)(xb + (size_t)N * D),
                                      (unsigned*)(h1b + (size_t)N * D));

    // ---- binned ELL build ----
    const int e4_total   = E >> 2;
    const int bin_blocks = (e4_total + 1023) / 1024 > 0 ? (e4_total + 1023) / 1024 : 1;
    hipMemsetAsync(gcur, 0, 512 * sizeof(int), stream);
    bin_kernel<<<bin_blocks, 256, 0, stream>>>(src, dst, gcur, gbucket, E, NB);
    ellify_kernel<<<NB, 256, 0, stream>>>(gcur, gbucket, cnt, edge_idx, N);

    const int gather_blocks  = (N + 31) / 32;   // 8 nodes/wave, 4 waves/block
    const int combine_blocks = 512;

    // ---- layer 1 ----
    gather_kernel<<<gather_blocks, 256, 0, stream>>>(xb, cnt, edge_idx, aggb, N);
    combine_kernel<<<combine_blocks, 256, 0, stream>>>(xb, aggb, Ws1, Wn1, b1,
                                                       nullptr, h1b, N);
    // ---- layer 2 ----
    gather_kernel<<<gather_blocks, 256, 0, stream>>>(h1b, cnt, edge_idx, aggb, N);
    combine_kernel<<<combine_blocks, 256, 0, stream>>>(h1b, aggb, Ws2, Wn2, b2,
                                                       out, nullptr, N);
}

// Round 2
// 212.196 us; speedup vs baseline: 1.3905x; 1.3905x over previous
//
#include <hip/hip_runtime.h>
#include <hip/hip_bf16.h>

// GraphSAGE 2-layer, mean agg, D=64, fp32 in/out.
// R9: all intermediate node features stored as bf16 (x_bf16, agg, h1) —
//     halves the random-gather traffic (128 B rows) and feeds MFMA directly.
// R10: gather restructured for memory-level parallelism (sentinel-padded
//     ELL rows -> branchless 8-load bursts; uint4 loads, 8 nodes/wave).
//     REGRESSED: __launch_bounds__(256,8) capped VGPRs at 64, allocator
//     landed at 32 + scratch spills (WRITE_SIZE 12.5->124 MB — the spill
//     stream). Structure was right, register budget wasn't.
// R11: same structure, __launch_bounds__(256,4) (128-VGPR budget) + named
//     scalar accumulators. 8 uint4 loads stay in registers -> true MLP.

#define D 64
#define CAP 64          // ELL row capacity
#define BNODES 256      // nodes per bucket (bucket = dst >> 8)
#define BCAP 4736       // bucket edge capacity: Poisson(4096), +10 sigma
#define MAXNB 512

typedef __bf16 bf16x8 __attribute__((ext_vector_type(8)));
typedef float  f32x4  __attribute__((ext_vector_type(4)));

__device__ __forceinline__ unsigned pack2(float a, float b) {
    __hip_bfloat162 t = __float22bfloat162_rn(make_float2(a, b));
    return *(unsigned*)&t;
}
__device__ __forceinline__ unsigned short f2b(float f) {
    __hip_bfloat16 b = __float2bfloat16(f);
    return *(unsigned short*)&b;
}

// ---- x -> bf16 ----------------------------------------------------------

__global__ void __launch_bounds__(256)
cvt_kernel(const float4* __restrict__ x, uint4* __restrict__ y, int n8) {
    int i = blockIdx.x * blockDim.x + threadIdx.x;
    if (i < n8) {
        float4 a = x[2 * i], b = x[2 * i + 1];
        uint4 o;
        o.x = pack2(a.x, a.y);
        o.y = pack2(a.z, a.w);
        o.z = pack2(b.x, b.y);
        o.w = pack2(b.z, b.w);
        y[i] = o;
    }
}

// ---- zero the sentinel row (index N) of xb and h1b ----------------------

__global__ void __launch_bounds__(64)
zrow_kernel(unsigned* __restrict__ a, unsigned* __restrict__ b) {
    int t = threadIdx.x;
    if (t < 32) a[t] = 0u;
    else        b[t - 32] = 0u;
}

// ---- Phase 1: bin edges by dst range ------------------------------------

__global__ void __launch_bounds__(256)
bin_kernel(const int* __restrict__ src, const int* __restrict__ dst,
           int* __restrict__ gcur, int* __restrict__ gbucket, int E, int NB) {
    __shared__ int hist[MAXNB];
    for (int i = threadIdx.x; i < NB; i += 256) hist[i] = 0;
    __syncthreads();

    const int t        = threadIdx.x;
    const int e4_total = E >> 2;
    const int base4    = blockIdx.x * 1024;

    int4 sv[4], dv[4];
    bool have[4];
    #pragma unroll
    for (int k = 0; k < 4; ++k) {
        int i4 = base4 + t + k * 256;
        have[k] = i4 < e4_total;
        if (have[k]) {
            sv[k] = ((const int4*)src)[i4];
            dv[k] = ((const int4*)dst)[i4];
        }
    }

    #pragma unroll
    for (int k = 0; k < 4; ++k) if (have[k]) {
        atomicAdd(&hist[dv[k].x >> 8], 1);
        atomicAdd(&hist[dv[k].y >> 8], 1);
        atomicAdd(&hist[dv[k].z >> 8], 1);
        atomicAdd(&hist[dv[k].w >> 8], 1);
    }

    int  tail_s = 0, tail_d = 0;
    bool have_tail = false;
    if (blockIdx.x == 0) {
        int e = (e4_total << 2) + t;
        if (e < E) {
            tail_s = src[e]; tail_d = dst[e]; have_tail = true;
            atomicAdd(&hist[tail_d >> 8], 1);
        }
    }
    __syncthreads();

    for (int i = threadIdx.x; i < NB; i += 256) {
        int c = hist[i];
        hist[i] = (c > 0) ? atomicAdd(&gcur[i], c) : 0;
    }
    __syncthreads();

    #pragma unroll
    for (int k = 0; k < 4; ++k) if (have[k]) {
        int4 s = sv[k], d = dv[k];
        int b, p;
        b = d.x >> 8; p = atomicAdd(&hist[b], 1); if (p < BCAP) gbucket[b * BCAP + p] = ((d.x & 255) << 17) | s.x;
        b = d.y >> 8; p = atomicAdd(&hist[b], 1); if (p < BCAP) gbucket[b * BCAP + p] = ((d.y & 255) << 17) | s.y;
        b = d.z >> 8; p = atomicAdd(&hist[b], 1); if (p < BCAP) gbucket[b * BCAP + p] = ((d.z & 255) << 17) | s.z;
        b = d.w >> 8; p = atomicAdd(&hist[b], 1); if (p < BCAP) gbucket[b * BCAP + p] = ((d.w & 255) << 17) | s.w;
    }
    if (have_tail) {
        int b = tail_d >> 8, p = atomicAdd(&hist[b], 1);
        if (p < BCAP) gbucket[b * BCAP + p] = ((tail_d & 255) << 17) | tail_s;
    }
}

// ---- Phase 2: per-bucket ELL build (64 KB L2-resident window) -----------
// Pads each node's edge list up to a multiple of 8 with sentinel index N
// (an all-zero feature row) so the gather inner loop is branchless.

__global__ void __launch_bounds__(256)
ellify_kernel(const int* __restrict__ gcur, const int* __restrict__ gbucket,
              int* __restrict__ cnt, int* __restrict__ edge_idx, int N) {
    __shared__ int scnt[BNODES];
    scnt[threadIdx.x] = 0;
    __syncthreads();

    const int b     = blockIdx.x;
    const int ne    = min(gcur[b], BCAP);
    const int node0 = b << 8;

    for (int e = threadIdx.x; e < ne; e += 256) {
        int p   = gbucket[b * BCAP + e];
        int s   = p & 0x1FFFF;
        int ld  = p >> 17;
        int pos = atomicAdd(&scnt[ld], 1);
        if (pos < CAP) edge_idx[(size_t)(node0 + ld) * CAP + pos] = s;
    }
    __syncthreads();

    int node = node0 + threadIdx.x;
    if (node < N) {
        int raw = scnt[threadIdx.x];
        cnt[node] = raw;
        int c  = min(raw, CAP);
        int c8 = (c + 7) & ~7;            // <= CAP since CAP % 8 == 0
        for (int p = c; p < c8; ++p)
            edge_idx[(size_t)node * CAP + p] = N;   // sentinel: zero row
    }
}

// ---- Gather (bf16 rows): agg[n] = mean of neighbor rows -----------------
// 8 lanes per node; lane q covers bytes [16q, 16q+16) of the 128 B row.
// Bursts of 8 edges, all loads unconditional (sentinel-padded lists).
// launch_bounds(256,4): 128-VGPR budget so all 8 uint4 stay live (no spill).

__device__ __forceinline__ void acc8(float& a0, float& a1, float& a2, float& a3,
                                     float& a4, float& a5, float& a6, float& a7,
                                     uint4 u) {
    a0 += __uint_as_float(u.x << 16);
    a1 += __uint_as_float(u.x & 0xffff0000u);
    a2 += __uint_as_float(u.y << 16);
    a3 += __uint_as_float(u.y & 0xffff0000u);
    a4 += __uint_as_float(u.z << 16);
    a5 += __uint_as_float(u.z & 0xffff0000u);
    a6 += __uint_as_float(u.w << 16);
    a7 += __uint_as_float(u.w & 0xffff0000u);
}

__global__ void __launch_bounds__(256, 4)
gather_kernel(const unsigned short* __restrict__ h,
              const int* __restrict__ cnt,
              const int* __restrict__ edge_idx,
              unsigned short* __restrict__ agg, int N) {
    const int lane = threadIdx.x & 63;
    const int q    = lane & 7;                  // 8 lanes x 16 B = 128 B row
    const int g    = lane >> 3;                 // 8 nodes per wave
    const int wave = blockIdx.x * (blockDim.x >> 6) + (threadIdx.x >> 6);
    const int node = wave * 8 + g;
    if (node >= N) return;

    const uint4* __restrict__ h4 = (const uint4*)h;   // row = 8 uint4

    const int count = min(cnt[node], CAP);
    const int c8    = (count + 7) & ~7;
    const int start = node * CAP;

    float a0 = 0.f, a1 = 0.f, a2 = 0.f, a3 = 0.f;
    float a4 = 0.f, a5 = 0.f, a6 = 0.f, a7 = 0.f;

    for (int j = 0; j < c8; j += 8) {
        const int sreg = edge_idx[start + j + q];
        const int b0 = g << 3;
        const int s0 = __shfl(sreg, b0 + 0, 64);
        const int s1 = __shfl(sreg, b0 + 1, 64);
        const int s2 = __shfl(sreg, b0 + 2, 64);
        const int s3 = __shfl(sreg, b0 + 3, 64);
        const int s4 = __shfl(sreg, b0 + 4, 64);
        const int s5 = __shfl(sreg, b0 + 5, 64);
        const int s6 = __shfl(sreg, b0 + 6, 64);
        const int s7 = __shfl(sreg, b0 + 7, 64);
        // 8 unconditional loads -> 8 vmem instrs in flight, 8 cachelines each
        uint4 u0 = h4[(size_t)s0 * 8 + q];
        uint4 u1 = h4[(size_t)s1 * 8 + q];
        uint4 u2 = h4[(size_t)s2 * 8 + q];
        uint4 u3 = h4[(size_t)s3 * 8 + q];
        uint4 u4 = h4[(size_t)s4 * 8 + q];
        uint4 u5 = h4[(size_t)s5 * 8 + q];
        uint4 u6 = h4[(size_t)s6 * 8 + q];
        uint4 u7 = h4[(size_t)s7 * 8 + q];
        acc8(a0, a1, a2, a3, a4, a5, a6, a7, u0);
        acc8(a0, a1, a2, a3, a4, a5, a6, a7, u1);
        acc8(a0, a1, a2, a3, a4, a5, a6, a7, u2);
        acc8(a0, a1, a2, a3, a4, a5, a6, a7, u3);
        acc8(a0, a1, a2, a3, a4, a5, a6, a7, u4);
        acc8(a0, a1, a2, a3, a4, a5, a6, a7, u5);
        acc8(a0, a1, a2, a3, a4, a5, a6, a7, u6);
        acc8(a0, a1, a2, a3, a4, a5, a6, a7, u7);
    }

    const float inv = 1.0f / fmaxf((float)count, 1.0f);
    uint4 o;
    o.x = pack2(a0 * inv, a1 * inv);
    o.y = pack2(a2 * inv, a3 * inv);
    o.z = pack2(a4 * inv, a5 * inv);
    o.w = pack2(a6 * inv, a7 * inv);
    ((uint4*)agg)[node * 8 + q] = o;
}

// ---- Combine (MFMA): out = [h|agg] @ [Wself;Wneigh] + b -----------------
// A-frag (16x16x32 bf16): row m = lane&15,  k = quad*8 + j
// C/D:                    col  = lane&15,  row = quad*4 + reg

__device__ __forceinline__ bf16x8 cvt8(float4 a, float4 b) {
    union { bf16x8 v; __hip_bfloat162 p[4]; } u;
    u.p[0] = __float22bfloat162_rn(make_float2(a.x, a.y));
    u.p[1] = __float22bfloat162_rn(make_float2(a.z, a.w));
    u.p[2] = __float22bfloat162_rn(make_float2(b.x, b.y));
    u.p[3] = __float22bfloat162_rn(make_float2(b.z, b.w));
    return u.v;
}
__device__ __forceinline__ bf16x8 asbf(uint4 u) {
    union { uint4 a; bf16x8 v; } c; c.a = u; return c.v;
}

__global__ void __launch_bounds__(256)
combine_kernel(const unsigned short* __restrict__ h,
               const unsigned short* __restrict__ agg,
               const float* __restrict__ Wself,
               const float* __restrict__ Wneigh,
               const float* __restrict__ bias,
               float* __restrict__ out_f32,
               unsigned short* __restrict__ out_bf16, int N) {
    const int lane = threadIdx.x & 63;
    const int col  = lane & 15;
    const int quad = lane >> 4;
    const int wave = blockIdx.x * (blockDim.x >> 6) + (threadIdx.x >> 6);
    const int n_waves = gridDim.x * (blockDim.x >> 6);

    // B fragments: Bf[nt][kk], n = nt*16+col, k = kk*32 + quad*8 + j.
    bf16x8 Bf[4][4];
    #pragma unroll
    for (int nt = 0; nt < 4; ++nt) {
        const int n = nt * 16 + col;
        #pragma unroll
        for (int kk = 0; kk < 4; ++kk) {
            const float* W = (kk < 2) ? Wself : Wneigh;
            const int kbase = (kk & 1) * 32 + quad * 8;
            float w0 = W[(kbase + 0) * D + n];
            float w1 = W[(kbase + 1) * D + n];
            float w2 = W[(kbase + 2) * D + n];
            float w3 = W[(kbase + 3) * D + n];
            float w4 = W[(kbase + 4) * D + n];
            float w5 = W[(kbase + 5) * D + n];
            float w6 = W[(kbase + 6) * D + n];
            float w7 = W[(kbase + 7) * D + n];
            Bf[nt][kk] = cvt8(make_float4(w0, w1, w2, w3), make_float4(w4, w5, w6, w7));
        }
    }

    float bv[4];
    #pragma unroll
    for (int nt = 0; nt < 4; ++nt) bv[nt] = bias[nt * 16 + col];

    const uint4* __restrict__ h4 = (const uint4*)h;     // row = 8 uint4
    const uint4* __restrict__ a4 = (const uint4*)agg;

    const int tiles = (N + 15) >> 4;
    for (int t = wave; t < tiles; t += n_waves) {
        int row = t * 16 + col;
        if (row >= N) row = N - 1;   // clamp; stores are guarded

        // A-frags load directly as bf16x8 (one uint4 each)
        bf16x8 A0 = asbf(h4[(size_t)row * 8 + quad]);
        bf16x8 A1 = asbf(h4[(size_t)row * 8 + 4 + quad]);
        bf16x8 A2 = asbf(a4[(size_t)row * 8 + quad]);
        bf16x8 A3 = asbf(a4[(size_t)row * 8 + 4 + quad]);

        #pragma unroll
        for (int nt = 0; nt < 4; ++nt) {
            f32x4 acc = {bv[nt], bv[nt], bv[nt], bv[nt]};
            acc = __builtin_amdgcn_mfma_f32_16x16x32_bf16(A0, Bf[nt][0], acc, 0, 0, 0);
            acc = __builtin_amdgcn_mfma_f32_16x16x32_bf16(A1, Bf[nt][1], acc, 0, 0, 0);
            acc = __builtin_amdgcn_mfma_f32_16x16x32_bf16(A2, Bf[nt][2], acc, 0, 0, 0);
            acc = __builtin_amdgcn_mfma_f32_16x16x32_bf16(A3, Bf[nt][3], acc, 0, 0, 0);
            if (out_f32) {
                #pragma unroll
                for (int r = 0; r < 4; ++r) {
                    const int orow = t * 16 + quad * 4 + r;
                    if (orow < N) out_f32[(size_t)orow * D + nt * 16 + col] = acc[r];
                }
            } else {
                #pragma unroll
                for (int r = 0; r < 4; ++r) {
                    const int orow = t * 16 + quad * 4 + r;
                    if (orow < N) out_bf16[(size_t)orow * D + nt * 16 + col] = f2b(acc[r]);
                }
            }
        }
    }
}

// -------------------------------------------------------------------------

extern "C" void kernel_launch(void* const* d_in, const int* in_sizes, int n_in,
                              void* d_out, int out_size, void* d_ws, size_t ws_size,
                              hipStream_t stream) {
    const float* x   = (const float*)d_in[0];
    const int*   src = (const int*)d_in[1];
    const int*   dst = (const int*)d_in[2];
    const float* Ws1 = (const float*)d_in[3];
    const float* Wn1 = (const float*)d_in[4];
    const float* b1  = (const float*)d_in[5];
    const float* Ws2 = (const float*)d_in[6];
    const float* Wn2 = (const float*)d_in[7];
    const float* b2  = (const float*)d_in[8];

    const int N = in_sizes[0] / D;   // 100000
    const int E = in_sizes[1];       // 1600000

    float* out = (float*)d_out;

    const int NB = (N + BNODES - 1) / BNODES;   // 391 buckets

    // Workspace: gcur[512] | cnt[N] | edge_idx[N*CAP] (25.6 MB) |
    //            xb[(N+1)*D] bf16 | h1b[(N+1)*D] bf16 | aggb[N*D] bf16
    // (xb/h1b carry one extra all-zero sentinel row at index N)
    // gbucket (7.4 MB) aliases aggb — dead before gather writes agg.
    int* gcur      = (int*)d_ws;
    int* cnt       = gcur + 512;
    int* edge_idx  = cnt + N;
    unsigned short* xb   = (unsigned short*)(edge_idx + (size_t)N * CAP);
    unsigned short* h1b  = xb + (size_t)(N + 1) * D;
    unsigned short* aggb = h1b + (size_t)(N + 1) * D;
    int* gbucket   = (int*)aggb;

    // ---- x -> bf16 (independent of build) + sentinel rows ----
    const int n8 = N * D / 8;
    cvt_kernel<<<(n8 + 255) / 256, 256, 0, stream>>>((const float4*)x, (uint4*)xb, n8);
    zrow_kernel<<<1, 64, 0, stream>>>((unsigned*)(xb + (size_t)N * D),
                                      (unsigned*)(h1b + (size_t)N * D));

    // ---- binned ELL build ----
    const int e4_total   = E >> 2;
    const int bin_blocks = (e4_total + 1023) / 1024 > 0 ? (e4_total + 1023) / 1024 : 1;
    hipMemsetAsync(gcur, 0, 512 * sizeof(int), stream);
    bin_kernel<<<bin_blocks, 256, 0, stream>>>(src, dst, gcur, gbucket, E, NB);
    ellify_kernel<<<NB, 256, 0, stream>>>(gcur, gbucket, cnt, edge_idx, N);

    const int gather_blocks  = (N + 31) / 32;   // 8 nodes/wave, 4 waves/block
    const int combine_blocks = 512;

    // ---- layer 1 ----
    gather_kernel<<<gather_blocks, 256, 0, stream>>>(xb, cnt, edge_idx, aggb, N);
    combine_kernel<<<combine_blocks, 256, 0, stream>>>(xb, aggb, Ws1, Wn1, b1,
                                                       nullptr, h1b, N);
    // ---- layer 2 ----
    gather_kernel<<<gather_blocks, 256, 0, stream>>>(h1b, cnt, edge_idx, aggb, N);
    combine_kernel<<<combine_blocks, 256, 0, stream>>>(h1b, aggb, Ws2, Wn2, b2,
                                                       out, nullptr, N);
}

// Round 3
// 207.761 us; speedup vs baseline: 1.4202x; 1.0213x over previous
//
#include <hip/hip_runtime.h>
#include <hip/hip_bf16.h>

// GraphSAGE 2-layer, mean agg, D=64, fp32 in/out.
// R9:  bf16 node features everywhere (halves random-gather traffic).
// R10: sentinel-padded branchless 8-load gather bursts. Regressed: VGPR cap
//      64 -> scratch spills (WRITE_SIZE 12.5->124 MB).
// R11: launch_bounds(256,4) -> no spill, gather ~43.5 -> ~33 us. 212 us.
// R12: dispatch-count attack. 10 enqueues -> 5:
//      - prep_kernel = bin + cvt + sentinel-zero (independent work, one grid)
//      - combine FUSED into gather: each wave gathers a 16-row tile (2x8
//        rounds, R11 inner loop), packs means to bf16 in regs, redistributes
//        to MFMA A-frag layout with 16 __shfl (no LDS), runs 16 MFMAs,
//        stores. Kills the agg HBM round-trip (~25 MB/layer) and 2 bubbles.

#define D 64
#define CAP 64          // ELL row capacity
#define BNODES 256      // nodes per bucket (bucket = dst >> 8)
#define BCAP 4736       // bucket edge capacity: Poisson(4096), +10 sigma
#define MAXNB 512

typedef __bf16 bf16x8 __attribute__((ext_vector_type(8)));
typedef float  f32x4  __attribute__((ext_vector_type(4)));

__device__ __forceinline__ unsigned pack2(float a, float b) {
    __hip_bfloat162 t = __float22bfloat162_rn(make_float2(a, b));
    return *(unsigned*)&t;
}
__device__ __forceinline__ unsigned short f2b(float f) {
    __hip_bfloat16 b = __float2bfloat16(f);
    return *(unsigned short*)&b;
}

// ---- prep: bin (blocks [0, bin_blocks)) + cvt/zrow (rest) ---------------

__global__ void __launch_bounds__(256)
prep_kernel(const float4* __restrict__ x, uint4* __restrict__ xb4,
            unsigned* __restrict__ xsent, unsigned* __restrict__ h1sent,
            const int* __restrict__ src, const int* __restrict__ dst,
            int* __restrict__ gcur, int* __restrict__ gbucket,
            int E, int NB, int n8, int bin_blocks) {
    const int bid = blockIdx.x;
    const int t   = threadIdx.x;

    if (bid < bin_blocks) {
        // ---------------- bin part ----------------
        __shared__ int hist[MAXNB];
        for (int i = t; i < NB; i += 256) hist[i] = 0;
        __syncthreads();

        const int e4_total = E >> 2;
        const int base4    = bid * 1024;

        int4 sv[4], dv[4];
        bool have[4];
        #pragma unroll
        for (int k = 0; k < 4; ++k) {
            int i4 = base4 + t + k * 256;
            have[k] = i4 < e4_total;
            if (have[k]) {
                sv[k] = ((const int4*)src)[i4];
                dv[k] = ((const int4*)dst)[i4];
            }
        }

        #pragma unroll
        for (int k = 0; k < 4; ++k) if (have[k]) {
            atomicAdd(&hist[dv[k].x >> 8], 1);
            atomicAdd(&hist[dv[k].y >> 8], 1);
            atomicAdd(&hist[dv[k].z >> 8], 1);
            atomicAdd(&hist[dv[k].w >> 8], 1);
        }

        int  tail_s = 0, tail_d = 0;
        bool have_tail = false;
        if (bid == 0) {
            int e = (e4_total << 2) + t;
            if (e < E) {
                tail_s = src[e]; tail_d = dst[e]; have_tail = true;
                atomicAdd(&hist[tail_d >> 8], 1);
            }
        }
        __syncthreads();

        for (int i = t; i < NB; i += 256) {
            int c = hist[i];
            hist[i] = (c > 0) ? atomicAdd(&gcur[i], c) : 0;
        }
        __syncthreads();

        #pragma unroll
        for (int k = 0; k < 4; ++k) if (have[k]) {
            int4 s = sv[k], d = dv[k];
            int b, p;
            b = d.x >> 8; p = atomicAdd(&hist[b], 1); if (p < BCAP) gbucket[b * BCAP + p] = ((d.x & 255) << 17) | s.x;
            b = d.y >> 8; p = atomicAdd(&hist[b], 1); if (p < BCAP) gbucket[b * BCAP + p] = ((d.y & 255) << 17) | s.y;
            b = d.z >> 8; p = atomicAdd(&hist[b], 1); if (p < BCAP) gbucket[b * BCAP + p] = ((d.z & 255) << 17) | s.z;
            b = d.w >> 8; p = atomicAdd(&hist[b], 1); if (p < BCAP) gbucket[b * BCAP + p] = ((d.w & 255) << 17) | s.w;
        }
        if (have_tail) {
            int b = tail_d >> 8, p = atomicAdd(&hist[b], 1);
            if (p < BCAP) gbucket[b * BCAP + p] = ((tail_d & 255) << 17) | tail_s;
        }
        return;
    }

    // ---------------- cvt part ----------------
    const int cb = bid - bin_blocks;
    const int i  = cb * 256 + t;
    if (i < n8) {
        float4 a = x[2 * i], b = x[2 * i + 1];
        uint4 o;
        o.x = pack2(a.x, a.y);
        o.y = pack2(a.z, a.w);
        o.z = pack2(b.x, b.y);
        o.w = pack2(b.z, b.w);
        xb4[i] = o;
    }
    if (cb == 0 && t < 64) {                 // sentinel rows (index N) = 0
        if (t < 32) xsent[t] = 0u;
        else        h1sent[t - 32] = 0u;
    }
}

// ---- Phase 2: per-bucket ELL build (sentinel-padded to multiple of 8) ---

__global__ void __launch_bounds__(256)
ellify_kernel(const int* __restrict__ gcur, const int* __restrict__ gbucket,
              int* __restrict__ cnt, int* __restrict__ edge_idx, int N) {
    __shared__ int scnt[BNODES];
    scnt[threadIdx.x] = 0;
    __syncthreads();

    const int b     = blockIdx.x;
    const int ne    = min(gcur[b], BCAP);
    const int node0 = b << 8;

    for (int e = threadIdx.x; e < ne; e += 256) {
        int p   = gbucket[b * BCAP + e];
        int s   = p & 0x1FFFF;
        int ld  = p >> 17;
        int pos = atomicAdd(&scnt[ld], 1);
        if (pos < CAP) edge_idx[(size_t)(node0 + ld) * CAP + pos] = s;
    }
    __syncthreads();

    int node = node0 + threadIdx.x;
    if (node < N) {
        int raw = scnt[threadIdx.x];
        cnt[node] = raw;
        int c  = min(raw, CAP);
        int c8 = (c + 7) & ~7;
        for (int p = c; p < c8; ++p)
            edge_idx[(size_t)node * CAP + p] = N;   // sentinel: zero row
    }
}

// ---- fused gather + combine ---------------------------------------------
// Per wave, per 16-row tile:
//   round p in {0,1}: gather mean row (p*8+g) with the R11 burst loop
//     (8 lanes x uint4 per row, branchless 8-load bursts), pack to bf16 P_p.
//   redistribute P0/P1 -> MFMA A2/A3 frags via 16 __shfl (no LDS):
//     target lane t (m=t&15, quad=t>>4) <- src lane ((t&7)<<3)+quad (+4 for
//     A3), round m>>3.  A0/A1 (h row) loaded direct from global.
//   16 MFMAs + guarded stores.

__device__ __forceinline__ void acc8(float& a0, float& a1, float& a2, float& a3,
                                     float& a4, float& a5, float& a6, float& a7,
                                     uint4 u) {
    a0 += __uint_as_float(u.x << 16);
    a1 += __uint_as_float(u.x & 0xffff0000u);
    a2 += __uint_as_float(u.y << 16);
    a3 += __uint_as_float(u.y & 0xffff0000u);
    a4 += __uint_as_float(u.z << 16);
    a5 += __uint_as_float(u.z & 0xffff0000u);
    a6 += __uint_as_float(u.w << 16);
    a7 += __uint_as_float(u.w & 0xffff0000u);
}

__device__ __forceinline__ uint4 gather_row8(const uint4* __restrict__ h4,
                                             const int* __restrict__ cnt,
                                             const int* __restrict__ edge_idx,
                                             int node, int N, int q, int g) {
    const int count = (node < N) ? min(cnt[node], CAP) : 0;
    const int c8    = (count + 7) & ~7;
    const int start = node * CAP;
    const int b0    = g << 3;

    float a0 = 0.f, a1 = 0.f, a2 = 0.f, a3 = 0.f;
    float a4 = 0.f, a5 = 0.f, a6 = 0.f, a7 = 0.f;

    for (int j = 0; j < c8; j += 8) {
        const int sreg = edge_idx[start + j + q];
        const int s0 = __shfl(sreg, b0 + 0, 64);
        const int s1 = __shfl(sreg, b0 + 1, 64);
        const int s2 = __shfl(sreg, b0 + 2, 64);
        const int s3 = __shfl(sreg, b0 + 3, 64);
        const int s4 = __shfl(sreg, b0 + 4, 64);
        const int s5 = __shfl(sreg, b0 + 5, 64);
        const int s6 = __shfl(sreg, b0 + 6, 64);
        const int s7 = __shfl(sreg, b0 + 7, 64);
        uint4 u0 = h4[(size_t)s0 * 8 + q];
        uint4 u1 = h4[(size_t)s1 * 8 + q];
        uint4 u2 = h4[(size_t)s2 * 8 + q];
        uint4 u3 = h4[(size_t)s3 * 8 + q];
        uint4 u4 = h4[(size_t)s4 * 8 + q];
        uint4 u5 = h4[(size_t)s5 * 8 + q];
        uint4 u6 = h4[(size_t)s6 * 8 + q];
        uint4 u7 = h4[(size_t)s7 * 8 + q];
        acc8(a0, a1, a2, a3, a4, a5, a6, a7, u0);
        acc8(a0, a1, a2, a3, a4, a5, a6, a7, u1);
        acc8(a0, a1, a2, a3, a4, a5, a6, a7, u2);
        acc8(a0, a1, a2, a3, a4, a5, a6, a7, u3);
        acc8(a0, a1, a2, a3, a4, a5, a6, a7, u4);
        acc8(a0, a1, a2, a3, a4, a5, a6, a7, u5);
        acc8(a0, a1, a2, a3, a4, a5, a6, a7, u6);
        acc8(a0, a1, a2, a3, a4, a5, a6, a7, u7);
    }

    const float inv = 1.0f / fmaxf((float)count, 1.0f);
    uint4 o;
    o.x = pack2(a0 * inv, a1 * inv);
    o.y = pack2(a2 * inv, a3 * inv);
    o.z = pack2(a4 * inv, a5 * inv);
    o.w = pack2(a6 * inv, a7 * inv);
    return o;
}

__device__ __forceinline__ bf16x8 cvt8(float4 a, float4 b) {
    union { bf16x8 v; __hip_bfloat162 p[4]; } u;
    u.p[0] = __float22bfloat162_rn(make_float2(a.x, a.y));
    u.p[1] = __float22bfloat162_rn(make_float2(a.z, a.w));
    u.p[2] = __float22bfloat162_rn(make_float2(b.x, b.y));
    u.p[3] = __float22bfloat162_rn(make_float2(b.z, b.w));
    return u.v;
}
__device__ __forceinline__ bf16x8 asbf(uint4 u) {
    union { uint4 a; bf16x8 v; } c; c.a = u; return c.v;
}

__global__ void __launch_bounds__(256, 3)
fused_kernel(const unsigned short* __restrict__ h,
             const int* __restrict__ cnt,
             const int* __restrict__ edge_idx,
             const float* __restrict__ Wself,
             const float* __restrict__ Wneigh,
             const float* __restrict__ bias,
             float* __restrict__ out_f32,
             unsigned short* __restrict__ out_bf16, int N) {
    const int lane = threadIdx.x & 63;
    const int q    = lane & 7;
    const int g    = lane >> 3;
    const int col  = lane & 15;
    const int quad = lane >> 4;
    const int wave = blockIdx.x * (blockDim.x >> 6) + (threadIdx.x >> 6);
    const int n_waves = gridDim.x * (blockDim.x >> 6);

    // B fragments in VGPRs (per wave, reused across all tiles)
    bf16x8 Bf[4][4];
    #pragma unroll
    for (int nt = 0; nt < 4; ++nt) {
        const int n = nt * 16 + col;
        #pragma unroll
        for (int kk = 0; kk < 4; ++kk) {
            const float* W = (kk < 2) ? Wself : Wneigh;
            const int kbase = (kk & 1) * 32 + quad * 8;
            float w0 = W[(kbase + 0) * D + n];
            float w1 = W[(kbase + 1) * D + n];
            float w2 = W[(kbase + 2) * D + n];
            float w3 = W[(kbase + 3) * D + n];
            float w4 = W[(kbase + 4) * D + n];
            float w5 = W[(kbase + 5) * D + n];
            float w6 = W[(kbase + 6) * D + n];
            float w7 = W[(kbase + 7) * D + n];
            Bf[nt][kk] = cvt8(make_float4(w0, w1, w2, w3), make_float4(w4, w5, w6, w7));
        }
    }

    float bv[4];
    #pragma unroll
    for (int nt = 0; nt < 4; ++nt) bv[nt] = bias[nt * 16 + col];

    const uint4* __restrict__ h4 = (const uint4*)h;   // row = 8 uint4

    const int tiles = (N + 15) >> 4;
    for (int t = wave; t < tiles; t += n_waves) {
        // ---- gather the tile's 16 mean-rows (2 rounds of 8) ----
        uint4 P0 = gather_row8(h4, cnt, edge_idx, t * 16 + g,     N, q, g);

        int row = t * 16 + col;
        if (row >= N) row = N - 1;                    // stores are guarded
        uint4 A0u = h4[(size_t)row * 8 + quad];
        uint4 A1u = h4[(size_t)row * 8 + 4 + quad];

        uint4 P1 = gather_row8(h4, cnt, edge_idx, t * 16 + 8 + g, N, q, g);

        // ---- redistribute P0/P1 -> A2/A3 fragments (16 shfl, no LDS) ----
        const int srcA2 = ((lane & 7) << 3) + quad;
        const int srcA3 = srcA2 + 4;
        const bool hi   = (lane & 8) != 0;            // m >= 8 -> round 1
        uint4 A2u, A3u;
        {
            unsigned l0 = __shfl(P0.x, srcA2, 64), h0 = __shfl(P1.x, srcA2, 64);
            unsigned l1 = __shfl(P0.y, srcA2, 64), h1 = __shfl(P1.y, srcA2, 64);
            unsigned l2 = __shfl(P0.z, srcA2, 64), h2 = __shfl(P1.z, srcA2, 64);
            unsigned l3 = __shfl(P0.w, srcA2, 64), h3 = __shfl(P1.w, srcA2, 64);
            A2u.x = hi ? h0 : l0;  A2u.y = hi ? h1 : l1;
            A2u.z = hi ? h2 : l2;  A2u.w = hi ? h3 : l3;
        }
        {
            unsigned l0 = __shfl(P0.x, srcA3, 64), h0 = __shfl(P1.x, srcA3, 64);
            unsigned l1 = __shfl(P0.y, srcA3, 64), h1 = __shfl(P1.y, srcA3, 64);
            unsigned l2 = __shfl(P0.z, srcA3, 64), h2 = __shfl(P1.z, srcA3, 64);
            unsigned l3 = __shfl(P0.w, srcA3, 64), h3 = __shfl(P1.w, srcA3, 64);
            A3u.x = hi ? h0 : l0;  A3u.y = hi ? h1 : l1;
            A3u.z = hi ? h2 : l2;  A3u.w = hi ? h3 : l3;
        }

        bf16x8 A0 = asbf(A0u), A1 = asbf(A1u);
        bf16x8 A2 = asbf(A2u), A3 = asbf(A3u);

        // ---- combine: 16 MFMAs + stores ----
        #pragma unroll
        for (int nt = 0; nt < 4; ++nt) {
            f32x4 acc = {bv[nt], bv[nt], bv[nt], bv[nt]};
            acc = __builtin_amdgcn_mfma_f32_16x16x32_bf16(A0, Bf[nt][0], acc, 0, 0, 0);
            acc = __builtin_amdgcn_mfma_f32_16x16x32_bf16(A1, Bf[nt][1], acc, 0, 0, 0);
            acc = __builtin_amdgcn_mfma_f32_16x16x32_bf16(A2, Bf[nt][2], acc, 0, 0, 0);
            acc = __builtin_amdgcn_mfma_f32_16x16x32_bf16(A3, Bf[nt][3], acc, 0, 0, 0);
            if (out_f32) {
                #pragma unroll
                for (int r = 0; r < 4; ++r) {
                    const int orow = t * 16 + quad * 4 + r;
                    if (orow < N) out_f32[(size_t)orow * D + nt * 16 + col] = acc[r];
                }
            } else {
                #pragma unroll
                for (int r = 0; r < 4; ++r) {
                    const int orow = t * 16 + quad * 4 + r;
                    if (orow < N) out_bf16[(size_t)orow * D + nt * 16 + col] = f2b(acc[r]);
                }
            }
        }
    }
}

// -------------------------------------------------------------------------

extern "C" void kernel_launch(void* const* d_in, const int* in_sizes, int n_in,
                              void* d_out, int out_size, void* d_ws, size_t ws_size,
                              hipStream_t stream) {
    const float* x   = (const float*)d_in[0];
    const int*   src = (const int*)d_in[1];
    const int*   dst = (const int*)d_in[2];
    const float* Ws1 = (const float*)d_in[3];
    const float* Wn1 = (const float*)d_in[4];
    const float* b1  = (const float*)d_in[5];
    const float* Ws2 = (const float*)d_in[6];
    const float* Wn2 = (const float*)d_in[7];
    const float* b2  = (const float*)d_in[8];

    const int N = in_sizes[0] / D;   // 100000
    const int E = in_sizes[1];       // 1600000

    float* out = (float*)d_out;

    const int NB = (N + BNODES - 1) / BNODES;   // 391 buckets

    // Workspace: gcur[512] | cnt[N] | edge_idx[N*CAP] (25.6 MB) |
    //            xb[(N+1)*D] bf16 | h1b[(N+1)*D] bf16 | gbucket (7.4 MB)
    // (no agg buffer anymore — combine is fused into gather)
    int* gcur      = (int*)d_ws;
    int* cnt       = gcur + 512;
    int* edge_idx  = cnt + N;
    unsigned short* xb   = (unsigned short*)(edge_idx + (size_t)N * CAP);
    unsigned short* h1b  = xb + (size_t)(N + 1) * D;
    int* gbucket   = (int*)(h1b + (size_t)(N + 1) * D);

    const int n8         = N * D / 8;
    const int cvt_blocks = (n8 + 255) / 256;
    const int e4_total   = E >> 2;
    const int bin_blocks = (e4_total + 1023) / 1024 > 0 ? (e4_total + 1023) / 1024 : 1;

    hipMemsetAsync(gcur, 0, 512 * sizeof(int), stream);

    // ---- prep: bin + cvt + sentinel zero, one dispatch ----
    prep_kernel<<<bin_blocks + cvt_blocks, 256, 0, stream>>>(
        (const float4*)x, (uint4*)xb,
        (unsigned*)(xb + (size_t)N * D), (unsigned*)(h1b + (size_t)N * D),
        src, dst, gcur, gbucket, E, NB, n8, bin_blocks);

    ellify_kernel<<<NB, 256, 0, stream>>>(gcur, gbucket, cnt, edge_idx, N);

    const int tiles  = (N + 15) / 16;
    const int fblocks = (tiles + 3) / 4;        // 1 tile per wave

    // ---- layer 1 (fused gather+combine, bf16 out) ----
    fused_kernel<<<fblocks, 256, 0, stream>>>(xb, cnt, edge_idx, Ws1, Wn1, b1,
                                              nullptr, h1b, N);
    // ---- layer 2 (fused, fp32 out) ----
    fused_kernel<<<fblocks, 256, 0, stream>>>(h1b, cnt, edge_idx, Ws2, Wn2, b2,
                                              out, nullptr, N);
}